// Round 4
// baseline (253.268 us; speedup 1.0000x reference)
//
#include <hip/hip_runtime.h>
#include <math.h>

#define NB 16
#define NC 512
#define NK 128
#define SP 4096   // 64*64 spatial positions

typedef __attribute__((ext_vector_type(8))) short short8;
typedef __attribute__((ext_vector_type(4))) float f32x4;

__device__ inline unsigned short f2bf(float f) {
    unsigned int u = __builtin_bit_cast(unsigned int, f);
    u += 0x7fffu + ((u >> 16) & 1u);   // RNE
    return (unsigned short)(u >> 16);
}

// ---------------------------------------------------------------------------
// ws layout (float offsets):
//   [0    .. 2047 ]  SY, [2048..4095] SX1, [4096..6143] SX2
//   [6144 .. 22527]  sbr   : sigmoid outputs, 2 br * 16 b * 512 c
//   [22528.. 55295]  w0bf  : bf16 wb[k][c]                    (65536 ushort)
//   [55296.. 88063]  w1bf  : bf16 wa[k][64a+t]=wa[k][8t+a]    (65536 ushort)
// ---------------------------------------------------------------------------

__global__ __launch_bounds__(256) void prep_weights(
    const float* __restrict__ wa, const float* __restrict__ wb,
    unsigned short* __restrict__ w0, unsigned short* __restrict__ w1) {
    int e = blockIdx.x * 256 + threadIdx.x;   // 0..65535
    w0[e] = f2bf(wb[e]);                      // same [k][c] layout
    int k = e >> 9, rem = e & 511, q = rem >> 6, t = rem & 63;
    w1[e] = f2bf(wa[k * 512 + 8 * t + q]);
}

// ---------------------------------------------------------------------------
// Fused view1+view2 conv+mean. Block (j,b), 512 thr = 8 waves = 4 ph x 2 kq.
// Act LDS layout: elem L(q,hg,w,hl) = q*PLE + (hg*64+w)*HLP + hl
//   q = plane (x[b, 64q+j, :, :]), w = x 3rd idx, h = 16*hg + hl = x 4th idx.
// view1: pos h, i1' = 64p + w  (weights w1bf[k][64p+w] = wa[k][8w+p])
// view2: pos w2 (q2=w2&7, w2hi=w2>>3), i2' = 64a + t -> elem (q2, a*8+w2hi, t)
// B-fragments read directly from global (w1bf is L2-resident, 64 KB).
// ---------------------------------------------------------------------------
#define HLP 18                    // hl pitch (elems)
#define PLE (4 * 64 * HLP + 48)   // plane pitch = 4656 elems

__global__ __launch_bounds__(512, 4) void conv_fused12(
    const float* __restrict__ x, const unsigned short* __restrict__ w1bf,
    const float* __restrict__ ba, float* __restrict__ SX1, float* __restrict__ SX2) {
    __shared__ __align__(16) unsigned short actS[8 * PLE];   // 74496 B
    __shared__ float red1[NK];
    __shared__ float red2[NK];

    const int b = blockIdx.y;
    const int j = blockIdx.x;
    const int t = threadIdx.x;
    const int lane = t & 63;
    const int wv = t >> 6;
    const int ph = wv & 3;          // pos 16-group (view1: h; view2: w2)
    const int kq = wv >> 2;         // k-out half (64 k)
    const int lr = lane & 15;
    const int lg = lane >> 4;       // 0..3

    if (t < NK) { red1[t] = 0.f; red2[t] = 0.f; }

    // ---- stage all 8 planes as bf16, subtiled layout ----
#pragma unroll 4
    for (int it = 0; it < 16; ++it) {
        int idx = it * 512 + t;            // 8192 float4 chunks
        int q = idx >> 10, rem = idx & 1023;
        int w = rem >> 4, h4 = rem & 15;
        float4 v = *(const float4*)(x + (size_t)(b * NC + 64 * q + j) * SP + w * 64 + h4 * 4);
        int L = q * PLE + ((h4 >> 2) * 64 + w) * HLP + (h4 & 3) * 4;
        ushort2 lo, hi;
        lo.x = f2bf(v.x); lo.y = f2bf(v.y);
        hi.x = f2bf(v.z); hi.y = f2bf(v.w);
        *(ushort2*)&actS[L] = lo;
        *(ushort2*)&actS[L + 2] = hi;
    }
    __syncthreads();

    f32x4 acc1[4], acc2[4];
#pragma unroll
    for (int nt = 0; nt < 4; ++nt) { acc1[nt] = (f32x4)(0.f); acc2[nt] = (f32x4)(0.f); }

    for (int wc = 0; wc < 4; ++wc) {
#pragma unroll
        for (int kk = 0; kk < 4; ++kk) {
            const int ib = kk * 32 + lg * 8;    // i' base within 128-chunk
            const int hi8 = ib >> 6;            // 0/1
            const int w0 = ib & 63;

            // ---- B-frags straight from global (16 B/lane, L2-hit) ----
            short8 bf[4];
#pragma unroll
            for (int nt = 0; nt < 4; ++nt) {
                int krow = kq * 64 + nt * 16 + lr;
                bf[nt] = *(const short8*)(w1bf + (size_t)krow * 512 + wc * 128 + ib);
            }

            // ---- view1 A-frag: pos h = ph*16+lr; elems w = w0+e, plane qp ----
            const int qp = 2 * wc + hi8;
            const int base1 = qp * PLE + (ph * 64 + w0) * HLP + lr;
            short8 a1;
#pragma unroll
            for (int e = 0; e < 8; ++e) a1[e] = (short)actS[base1 + HLP * e];

            // ---- view2 A-frag: pos w2 = ph*16+lr; elems t = w0+e, contiguous ----
            const int a2i = 2 * wc + hi8;
            const int row2 = a2i * 8 + ph * 2 + (lr >> 3);
            const int q2 = lr & 7;
            const int L2 = q2 * PLE + ((w0 >> 4) * 64 + row2) * HLP + (w0 & 15);
            short8 a2;
            const unsigned int* p2 = (const unsigned int*)&actS[L2];
#pragma unroll
            for (int u = 0; u < 4; ++u) {
                unsigned int vv = p2[u];
                a2[2 * u] = (short)(vv & 0xffffu);
                a2[2 * u + 1] = (short)(vv >> 16);
            }

#pragma unroll
            for (int nt = 0; nt < 4; ++nt) {
                acc1[nt] = __builtin_amdgcn_mfma_f32_16x16x32_bf16(a1, bf[nt], acc1[nt], 0, 0, 0);
                acc2[nt] = __builtin_amdgcn_mfma_f32_16x16x32_bf16(a2, bf[nt], acc2[nt], 0, 0, 0);
            }
        }
    }

    // ---- epilogue: relu(acc+bias), sum the lane's 4 positions ----
#pragma unroll
    for (int nt = 0; nt < 4; ++nt) {
        int k = kq * 64 + nt * 16 + lr;
        float bv = ba[k];
        float s1 = 0.f, s2 = 0.f;
#pragma unroll
        for (int rr = 0; rr < 4; ++rr) {
            s1 += fmaxf(acc1[nt][rr] + bv, 0.f);
            s2 += fmaxf(acc2[nt][rr] + bv, 0.f);
        }
        atomicAdd(&red1[k], s1);
        atomicAdd(&red2[k], s2);
    }
    __syncthreads();
    if (t < NK) {
        atomicAdd(&SX1[b * NK + t], red1[t]);
        atomicAdd(&SX2[b * NK + t], red2[t]);
    }
}

// ---------------------------------------------------------------------------
// view0 conv: act staged swizzled in LDS (as round-3), weights from global.
// ---------------------------------------------------------------------------
__global__ __launch_bounds__(256, 4) void conv_mfma0(
    const float* __restrict__ x, const unsigned short* __restrict__ wbf,
    const float* __restrict__ bias, float* __restrict__ Ssum) {
    __shared__ __align__(16) unsigned short actS[64 * 128];   // 16 KB swizzled
    __shared__ float red[NK];

    const int b = blockIdx.y;
    const int g = blockIdx.x;
    const int t = threadIdx.x;
    const int wv = t >> 6;
    const int lane = t & 63;
    const int lr = lane & 15, lg = lane >> 4;

    if (t < NK) red[t] = 0.f;

    f32x4 acc[8];
#pragma unroll
    for (int n = 0; n < 8; ++n) acc[n] = (f32x4)(0.f);

    for (int ch = 0; ch < 4; ++ch) {
        // stage act chunk: 128 c-rows x 64 pos, float4 loads + transposed b16 writes
#pragma unroll
        for (int it = 0; it < 8; ++it) {
            int idx = it * 256 + t;         // 2048 float4
            int row = idx >> 4;             // c-local 0..127
            int p4 = idx & 15;
            float4 v = *(const float4*)(x + (size_t)(b * NC + ch * 128 + row) * SP + g * 64 + p4 * 4);
            float vv[4] = {v.x, v.y, v.z, v.w};
#pragma unroll
            for (int m = 0; m < 4; ++m) {
                int pos = p4 * 4 + m;
                int byte = pos * 256 + ((((row >> 3) ^ (pos & 7))) << 4) + (row & 7) * 2;
                *(unsigned short*)((char*)actS + byte) = f2bf(vv[m]);
            }
        }
        __syncthreads();
#pragma unroll
        for (int kk = 0; kk < 4; ++kk) {
            int prow = wv * 16 + lr;
            int ig = 4 * kk + lg;
            short8 a = *(const short8*)((const char*)actS + prow * 256 +
                                        ((ig ^ (prow & 7)) << 4));
#pragma unroll
            for (int n = 0; n < 8; ++n) {
                int krow = n * 16 + lr;
                short8 bfr = *(const short8*)(wbf + (size_t)krow * 512 + ch * 128 + kk * 32 + lg * 8);
                acc[n] = __builtin_amdgcn_mfma_f32_16x16x32_bf16(a, bfr, acc[n], 0, 0, 0);
            }
        }
        __syncthreads();
    }

#pragma unroll
    for (int n = 0; n < 8; ++n) {
        int k = n * 16 + lr;
        float bv = bias[k];
        float s = 0.f;
#pragma unroll
        for (int rr = 0; rr < 4; ++rr) s += fmaxf(acc[n][rr] + bv, 0.f);
        atomicAdd(&red[k], s);
    }
    __syncthreads();
    if (t < NK) atomicAdd(&Ssum[b * NK + t], red[t]);
}

// Per-(b,branch) MLP chain
__global__ __launch_bounds__(256) void chain_kernel(
    const float* __restrict__ Sy, const float* __restrict__ Sx1,
    const float* __restrict__ Sx2, const float* __restrict__ wd,
    const float* __restrict__ wc1, const float* __restrict__ bc1,
    const float* __restrict__ wc2, const float* __restrict__ bc2,
    float* __restrict__ sbr) {
    __shared__ float m[128];
    __shared__ float ap[512];
    __shared__ float z[128];
    const int b = blockIdx.x, br = blockIdx.y, t = threadIdx.x;
    const float* Sx = (br == 0) ? Sx1 : Sx2;
    const float inv = 1.0f / 4096.0f;

    if (t < 128) m[t] = (Sy[b * NK + t] + Sx[b * NK + t]) * inv;
    __syncthreads();
    for (int c = t; c < NC; c += 256) {
        float v = 0.f;
        for (int k = 0; k < NK; ++k) v += wd[c * NK + k] * m[k];
        ap[c] = v;
    }
    __syncthreads();
    if (t < 128) {
        float v = bc1[t];
        for (int c = 0; c < NC; ++c) v += wc1[t * NC + c] * ap[c];
        z[t] = fmaxf(v, 0.f);
    }
    __syncthreads();
    for (int c = t; c < NC; c += 256) {
        float v = bc2[c];
        for (int k = 0; k < NK; ++k) v += wc2[c * NK + k] * z[k];
        sbr[(br * NB + b) * NC + c] = 1.f / (1.f + expf(-v));
    }
}

// out[b,c,s] = x[b,c,s] + s1[b,c] + s2[b,c]
__global__ __launch_bounds__(256) void final_add(
    const float* __restrict__ x, const float* __restrict__ sbr,
    float* __restrict__ out) {
    const int total4 = NB * NC * SP / 4;   // 8388608
    for (int i = blockIdx.x * 256 + threadIdx.x; i < total4; i += gridDim.x * 256) {
        int flat = i * 4;
        int bc = flat >> 12;
        int b = bc >> 9, c = bc & 511;
        float s = sbr[b * NC + c] + sbr[NB * NC + b * NC + c];
        float4 xv = ((const float4*)x)[i];
        float4 o = {xv.x + s, xv.y + s, xv.z + s, xv.w + s};
        ((float4*)out)[i] = o;
    }
}

extern "C" void kernel_launch(void* const* d_in, const int* in_sizes, int n_in,
                              void* d_out, int out_size, void* d_ws, size_t ws_size,
                              hipStream_t stream) {
    const float* x   = (const float*)d_in[0];
    const float* wa  = (const float*)d_in[1];
    const float* ba  = (const float*)d_in[2];
    const float* wb  = (const float*)d_in[3];
    const float* bb  = (const float*)d_in[4];
    const float* wd  = (const float*)d_in[5];
    const float* wc1 = (const float*)d_in[6];
    const float* bc1 = (const float*)d_in[7];
    const float* wc2 = (const float*)d_in[8];
    const float* bc2 = (const float*)d_in[9];
    float* out = (float*)d_out;

    float* ws  = (float*)d_ws;
    float* SY  = ws;
    float* SX1 = ws + 2048;
    float* SX2 = ws + 4096;
    float* sbr = ws + 6144;
    unsigned short* w0bf = (unsigned short*)(ws + 22528);
    unsigned short* w1bf = (unsigned short*)(ws + 55296);

    hipMemsetAsync(ws, 0, 6144 * sizeof(float), stream);
    prep_weights<<<256, 256, 0, stream>>>(wa, wb, w0bf, w1bf);
    conv_fused12<<<dim3(64, NB), 512, 0, stream>>>(x, w1bf, ba, SX1, SX2);
    conv_mfma0<<<dim3(64, NB), 256, 0, stream>>>(x, w0bf, bb, SY);
    chain_kernel<<<dim3(NB, 2), 256, 0, stream>>>(SY, SX1, SX2, wd, wc1, bc1, wc2, bc2, sbr);
    final_add<<<2048, 256, 0, stream>>>(x, sbr, out);
}

// Round 7
// 208.748 us; speedup vs baseline: 1.2133x; 1.2133x over previous
//
#include <hip/hip_runtime.h>
#include <math.h>

#define NB 16
#define NC 512
#define NK 128
#define SP 4096   // 64*64 spatial positions

typedef __attribute__((ext_vector_type(8))) short short8;
typedef __attribute__((ext_vector_type(4))) float f32x4;

__device__ inline unsigned short f2bf(float f) {
    unsigned int u = __builtin_bit_cast(unsigned int, f);
    u += 0x7fffu + ((u >> 16) & 1u);   // RNE
    return (unsigned short)(u >> 16);
}

// ---------------------------------------------------------------------------
// ws layout (float offsets):
//   [0..2047] SY  [2048..4095] SX1  [4096..6143] SX2
//   [6144..22527]  sbr (2 br * 16 b * 512 c)
//   [22528..55295] w0bf : bf16 wb[k][c]                  (65536 ushort)
//   [55296..88063] w1bf : bf16 wa[k][64a+t]=wa[k][8t+a]  (65536 ushort)
// ---------------------------------------------------------------------------

__global__ __launch_bounds__(256) void prep_weights(
    const float* __restrict__ wa, const float* __restrict__ wb,
    unsigned short* __restrict__ w0, unsigned short* __restrict__ w1) {
    int e = blockIdx.x * 256 + threadIdx.x;   // 0..65535
    w0[e] = f2bf(wb[e]);                      // natural [k][c]
    int k = e >> 9, rem = e & 511, q = rem >> 6, t = rem & 63;
    w1[e] = f2bf(wa[k * 512 + 8 * t + q]);
}

// ---------------------------------------------------------------------------
// Conv+mean, round-2-verified fragment math. Block (g,b), 256 thr = 4 waves
// = (kq = wv>>1: k-half) x (po = wv&1: pos-half). LDS act [64 pos][128 i]
// bf16, XOR-swizzled 16B granules: byte(pos,iloc) =
//    pos*256 + (((iloc>>3) ^ (pos&7))<<4) + (iloc&7)*2
// Weights [128 k][128 i] same swizzle. MFMA 16x16x32: A = act rows (pos),
// B = weight rows (k); D col = k-local (lane&15), row = pos (4*lg+rr).
// VIEW 0: i = c = ch*128+iloc;            act elem = x[b, c, g*64+pos]
// VIEW 1: i'= 128ch+iloc (qh=iloc>>6,w=iloc&63): x[b, 64*(2ch+qh)+g, w, pos]
// VIEW 2: i'= 128ch+64qh+lane; pos=cl*8+jh:      x[b, 8g+cl, 8*(2ch+qh)+jh, lane]
// Views 1,2 pair with w1bf (column-permuted wa), view 0 with w0bf.
// ---------------------------------------------------------------------------
template <int VIEW>
__global__ __launch_bounds__(256, 3) void conv_v(
    const float* __restrict__ x, const unsigned short* __restrict__ wbf,
    const float* __restrict__ bias, float* __restrict__ Ssum) {
    __shared__ __align__(16) unsigned short actS[64 * 128];   // 16 KB
    __shared__ __align__(16) unsigned short wS[128 * 128];    // 32 KB
    __shared__ float red[NK];

    const int b = blockIdx.y;
    const int g = blockIdx.x;
    const int t = threadIdx.x;
    const int lane = t & 63;
    const int wv = t >> 6;
    const int kq = wv >> 1;      // k half: 4 nt-tiles
    const int po = wv & 1;       // pos half: 2 pt-tiles
    const int lr = lane & 15;
    const int lg = lane >> 4;

    if (t < NK) red[t] = 0.f;

    f32x4 acc[2][4];
#pragma unroll
    for (int pt = 0; pt < 2; ++pt)
#pragma unroll
        for (int nt = 0; nt < 4; ++nt) acc[pt][nt] = (f32x4)(0.f);

    for (int ch = 0; ch < 4; ++ch) {
        if (ch) __syncthreads();   // prior chunk's readers done before overwrite

        // ---- stage act tile [64 pos][128 i] ----
        if (VIEW <= 1) {
            // 8 i-quads per thread: 4 channel-strided dword loads -> 1 b64 write
#pragma unroll
            for (int it = 0; it < 8; ++it) {
                int idx = it * 256 + t;        // 2048 quads
                int pos = idx & 63;            // = lane (coalesced)
                int q4 = idx >> 6;             // 0..31, wave-uniform
                float v[4];
#pragma unroll
                for (int e = 0; e < 4; ++e) {
                    int iloc = 4 * q4 + e;
                    size_t ga;
                    if (VIEW == 0) {
                        ga = (size_t)(b * NC + ch * 128 + iloc) * SP + g * 64 + pos;
                    } else {
                        int qh = iloc >> 6, w = iloc & 63;
                        ga = (size_t)(b * NC + 64 * (2 * ch + qh) + g) * SP + w * 64 + pos;
                    }
                    v[e] = x[ga];
                }
                ushort4 u;
                u.x = f2bf(v[0]); u.y = f2bf(v[1]); u.z = f2bf(v[2]); u.w = f2bf(v[3]);
                int byte = pos * 256 + (((q4 >> 1) ^ (pos & 7)) << 4) + (q4 & 1) * 8;
                *(ushort4*)((char*)actS + byte) = u;
            }
        } else {
            // round-2 verified scatter: lane -> iloc contiguous (conflict-free)
#pragma unroll
            for (int r = wv; r < 128; r += 4) {
                int cl = r >> 4, jh = (r >> 1) & 7, qh = r & 1;
                size_t ga = (size_t)(b * NC + 8 * g + cl) * SP + (8 * (2 * ch + qh) + jh) * 64 + lane;
                unsigned short v = f2bf(x[ga]);
                int pos = cl * 8 + jh;
                int iloc = 64 * qh + lane;
                int byte = pos * 256 + (((iloc >> 3) ^ (pos & 7)) << 4) + (iloc & 7) * 2;
                *(unsigned short*)((char*)actS + byte) = v;
            }
        }

        // ---- stage weight chunk [128 k][128 i] ----
#pragma unroll
        for (int it = 0; it < 8; ++it) {
            int gi = it * 256 + t;             // 2048 granules of 16 B
            int k = gi >> 4, gg = gi & 15;
            uint4 v = *(const uint4*)(wbf + (size_t)k * 512 + ch * 128 + gg * 8);
            *(uint4*)((char*)wS + k * 256 + ((gg ^ (k & 7)) << 4)) = v;
        }
        __syncthreads();

        // ---- MFMA: wave owns pos-tiles po*32..+32, k-tiles kq*64..+64 ----
#pragma unroll
        for (int kk = 0; kk < 4; ++kk) {
            const int ig = 4 * kk + lg;
            short8 a[2];
#pragma unroll
            for (int pt = 0; pt < 2; ++pt) {
                int prow = po * 32 + pt * 16 + lr;
                a[pt] = *(const short8*)((const char*)actS + prow * 256 + ((ig ^ (prow & 7)) << 4));
            }
            short8 bf[4];
#pragma unroll
            for (int nt = 0; nt < 4; ++nt) {
                int krow = kq * 64 + nt * 16 + lr;
                bf[nt] = *(const short8*)((const char*)wS + krow * 256 + ((ig ^ (krow & 7)) << 4));
            }
#pragma unroll
            for (int pt = 0; pt < 2; ++pt)
#pragma unroll
                for (int nt = 0; nt < 4; ++nt)
                    acc[pt][nt] = __builtin_amdgcn_mfma_f32_16x16x32_bf16(a[pt], bf[nt], acc[pt][nt], 0, 0, 0);
        }
    }

    // ---- epilogue: relu(acc+bias), sum this wave's 32 positions ----
#pragma unroll
    for (int nt = 0; nt < 4; ++nt) {
        int k = kq * 64 + nt * 16 + lr;
        float bv = bias[k];
        float s = 0.f;
#pragma unroll
        for (int pt = 0; pt < 2; ++pt)
#pragma unroll
            for (int rr = 0; rr < 4; ++rr)
                s += fmaxf(acc[pt][nt][rr] + bv, 0.f);
        atomicAdd(&red[k], s);
    }
    __syncthreads();
    if (t < NK) atomicAdd(&Ssum[b * NK + t], red[t]);
}

// Per-(b,branch) MLP chain
__global__ __launch_bounds__(256) void chain_kernel(
    const float* __restrict__ Sy, const float* __restrict__ Sx1,
    const float* __restrict__ Sx2, const float* __restrict__ wd,
    const float* __restrict__ wc1, const float* __restrict__ bc1,
    const float* __restrict__ wc2, const float* __restrict__ bc2,
    float* __restrict__ sbr) {
    __shared__ float m[128];
    __shared__ float ap[512];
    __shared__ float z[128];
    const int b = blockIdx.x, br = blockIdx.y, t = threadIdx.x;
    const float* Sx = (br == 0) ? Sx1 : Sx2;
    const float inv = 1.0f / 4096.0f;

    if (t < 128) m[t] = (Sy[b * NK + t] + Sx[b * NK + t]) * inv;
    __syncthreads();
    for (int c = t; c < NC; c += 256) {
        float v = 0.f;
        for (int k = 0; k < NK; ++k) v += wd[c * NK + k] * m[k];
        ap[c] = v;
    }
    __syncthreads();
    if (t < 128) {
        float v = bc1[t];
        for (int c = 0; c < NC; ++c) v += wc1[t * NC + c] * ap[c];
        z[t] = fmaxf(v, 0.f);
    }
    __syncthreads();
    for (int c = t; c < NC; c += 256) {
        float v = bc2[c];
        for (int k = 0; k < NK; ++k) v += wc2[c * NK + k] * z[k];
        sbr[(br * NB + b) * NC + c] = 1.f / (1.f + expf(-v));
    }
}

// out[b,c,s] = x[b,c,s] + s1[b,c] + s2[b,c]
__global__ __launch_bounds__(256) void final_add(
    const float* __restrict__ x, const float* __restrict__ sbr,
    float* __restrict__ out) {
    const int total4 = NB * NC * SP / 4;   // 8388608
    for (int i = blockIdx.x * 256 + threadIdx.x; i < total4; i += gridDim.x * 256) {
        int flat = i * 4;
        int bc = flat >> 12;
        int b = bc >> 9, c = bc & 511;
        float s = sbr[b * NC + c] + sbr[NB * NC + b * NC + c];
        float4 xv = ((const float4*)x)[i];
        float4 o = {xv.x + s, xv.y + s, xv.z + s, xv.w + s};
        ((float4*)out)[i] = o;
    }
}

extern "C" void kernel_launch(void* const* d_in, const int* in_sizes, int n_in,
                              void* d_out, int out_size, void* d_ws, size_t ws_size,
                              hipStream_t stream) {
    const float* x   = (const float*)d_in[0];
    const float* wa  = (const float*)d_in[1];
    const float* ba  = (const float*)d_in[2];
    const float* wb  = (const float*)d_in[3];
    const float* bb  = (const float*)d_in[4];
    const float* wd  = (const float*)d_in[5];
    const float* wc1 = (const float*)d_in[6];
    const float* bc1 = (const float*)d_in[7];
    const float* wc2 = (const float*)d_in[8];
    const float* bc2 = (const float*)d_in[9];
    float* out = (float*)d_out;

    float* ws  = (float*)d_ws;
    float* SY  = ws;
    float* SX1 = ws + 2048;
    float* SX2 = ws + 4096;
    float* sbr = ws + 6144;
    unsigned short* w0bf = (unsigned short*)(ws + 22528);
    unsigned short* w1bf = (unsigned short*)(ws + 55296);

    hipMemsetAsync(ws, 0, 6144 * sizeof(float), stream);
    prep_weights<<<256, 256, 0, stream>>>(wa, wb, w0bf, w1bf);
    conv_v<0><<<dim3(64, NB), 256, 0, stream>>>(x, w0bf, bb, SY);
    conv_v<1><<<dim3(64, NB), 256, 0, stream>>>(x, w1bf, ba, SX1);
    conv_v<2><<<dim3(64, NB), 256, 0, stream>>>(x, w1bf, ba, SX2);
    chain_kernel<<<dim3(NB, 2), 256, 0, stream>>>(SY, SX1, SX2, wd, wc1, bc1, wc2, bc2, sbr);
    final_add<<<2048, 256, 0, stream>>>(x, sbr, out);
}

// Round 8
// 173.918 us; speedup vs baseline: 1.4563x; 1.2003x over previous
//
#include <hip/hip_runtime.h>
#include <math.h>

#define NB 16
#define NC 512
#define NK 128
#define SP 4096   // 64*64 spatial positions

typedef __attribute__((ext_vector_type(8))) short short8;
typedef __attribute__((ext_vector_type(4))) float f32x4;

__device__ inline unsigned short f2bf(float f) {
    unsigned int u = __builtin_bit_cast(unsigned int, f);
    u += 0x7fffu + ((u >> 16) & 1u);   // RNE
    return (unsigned short)(u >> 16);
}

// ---------------------------------------------------------------------------
// ws layout (float offsets):
//   [0..2047] SY  [2048..4095] SX1  [4096..6143] SX2
//   [6144..22527]  sbr (2 br * 16 b * 512 c)
//   [22528..55295] wpre0 : wb pre-swizzled to per-wave B-frag order (65536 u16)
//   [55296..88063] wpre1 : wa (col-permuted) same order             (65536 u16)
//
// wpre element order: o = idx16*512 + lane*8 + el, where
//   idx16 = (ch*4 + kk)*8 + t8   (t8 = global k-tile = kq*4+nt)
//   k = t8*16 + (lane&15);  i = ch*128 + kk*32 + (lane>>4)*8 + el
// so a B-frag load = one dwordx4 of 64 lanes x 16 B contiguous (1 KB line).
// For wpre1 the logical column i' maps to wa column 8*(i'&63) + (i'>>6)
// (identical to the round-2/7-verified w1bf permutation).
// ---------------------------------------------------------------------------

__global__ __launch_bounds__(256) void prep_weights(
    const float* __restrict__ wa, const float* __restrict__ wb,
    unsigned short* __restrict__ w0, unsigned short* __restrict__ w1) {
    int o = blockIdx.x * 256 + threadIdx.x;   // 0..65535
    int idx16 = o >> 9;                        // (ch*4+kk)*8 + t8
    int lane = (o >> 3) & 63;
    int el = o & 7;
    int t8 = idx16 & 7;
    int kk = (idx16 >> 3) & 3;
    int ch = idx16 >> 5;
    int k = t8 * 16 + (lane & 15);
    int i = ch * 128 + kk * 32 + (lane >> 4) * 8 + el;
    w0[o] = f2bf(wb[k * 512 + i]);
    int col1 = 8 * (i & 63) + (i >> 6);
    w1[o] = f2bf(wa[k * 512 + col1]);
}

// ---------------------------------------------------------------------------
// Conv+mean, round-2/7-verified fragment math. Block (g,b), 256 thr = 4 waves
// = (kq = wv>>1: k-half) x (po = wv&1: pos-half). LDS act [64 pos][128 i]
// bf16, XOR-swizzled 16B granules: byte(pos, iloc) =
//    pos*256 + (((iloc>>3) ^ (pos&7))<<4) + (iloc&7)*2
// A = act rows (pos), B = weight rows (k) from wpre (global, L2-hot);
// D col = k-local (lane&15), row = pos (4*lg+rr).
// VIEW 0: i = c = ch*128+iloc;            act elem = x[b, c, g*64+pos]
// VIEW 1: i'= 128ch+iloc (qh=iloc>>6,w=iloc&63): x[b, 64*(2ch+qh)+g, w, pos]
// VIEW 2: i'= 128ch+64qh+lane; pos=cl*8+jh:      x[b, 8g+cl, 8*(2ch+qh)+jh, lane]
// ---------------------------------------------------------------------------
template <int VIEW>
__global__ __launch_bounds__(256, 4) void conv_v(
    const float* __restrict__ x, const unsigned short* __restrict__ wpre,
    const float* __restrict__ bias, float* __restrict__ Ssum) {
    __shared__ __align__(16) unsigned short actS[64 * 128];   // 16 KB
    __shared__ float red[NK];

    const int b = blockIdx.y;
    const int g = blockIdx.x;
    const int t = threadIdx.x;
    const int lane = t & 63;
    const int wv = t >> 6;
    const int kq = wv >> 1;      // k half: 4 nt-tiles
    const int po = wv & 1;       // pos half: 2 pt-tiles
    const int lr = lane & 15;
    const int lg = lane >> 4;

    if (t < NK) red[t] = 0.f;

    f32x4 acc[2][4];
#pragma unroll
    for (int pt = 0; pt < 2; ++pt)
#pragma unroll
        for (int nt = 0; nt < 4; ++nt) acc[pt][nt] = (f32x4)(0.f);

    for (int ch = 0; ch < 4; ++ch) {
        if (ch) __syncthreads();   // prior chunk's readers done before overwrite

        // ---- stage act tile [64 pos][128 i] (conflict-free b128 writes) ----
        if (VIEW <= 1) {
#pragma unroll
            for (int it = 0; it < 4; ++it) {
                int idx = it * 256 + t;        // 1024 granules
                int pos = idx & 63;            // = lane (coalesced loads)
                int gq = idx >> 6;             // 0..15, wave-uniform
                float v[8];
#pragma unroll
                for (int e = 0; e < 8; ++e) {
                    int iloc = 8 * gq + e;
                    size_t ga;
                    if (VIEW == 0) {
                        ga = (size_t)(b * NC + ch * 128 + iloc) * SP + g * 64 + pos;
                    } else {
                        int qh = iloc >> 6, w = iloc & 63;
                        ga = (size_t)(b * NC + 64 * (2 * ch + qh) + g) * SP + w * 64 + pos;
                    }
                    v[e] = x[ga];
                }
                short8 u;
#pragma unroll
                for (int e = 0; e < 8; ++e) u[e] = (short)f2bf(v[e]);
                int byte = pos * 256 + ((gq ^ (pos & 7)) << 4);
                *(short8*)((char*)actS + byte) = u;
            }
        } else {
            // verified scatter: lane -> iloc contiguous (conflict-free b16)
#pragma unroll
            for (int r = wv; r < 128; r += 4) {
                int cl = r >> 4, jh = (r >> 1) & 7, qh = r & 1;
                size_t ga = (size_t)(b * NC + 8 * g + cl) * SP + (8 * (2 * ch + qh) + jh) * 64 + lane;
                unsigned short v = f2bf(x[ga]);
                int pos = cl * 8 + jh;
                int iloc = 64 * qh + lane;
                int byte = pos * 256 + (((iloc >> 3) ^ (pos & 7)) << 4) + (iloc & 7) * 2;
                *(unsigned short*)((char*)actS + byte) = v;
            }
        }
        __syncthreads();

        // ---- MFMA: A from LDS, B straight from wpre (1 KB coalesced) ----
#pragma unroll
        for (int kk = 0; kk < 4; ++kk) {
            const int ig = 4 * kk + lg;
            short8 a[2];
#pragma unroll
            for (int pt = 0; pt < 2; ++pt) {
                int prow = po * 32 + pt * 16 + lr;
                a[pt] = *(const short8*)((const char*)actS + prow * 256 + ((ig ^ (prow & 7)) << 4));
            }
            short8 bf[4];
#pragma unroll
            for (int nt = 0; nt < 4; ++nt) {
                int idx16 = (ch * 4 + kk) * 8 + kq * 4 + nt;
                bf[nt] = *(const short8*)(wpre + (size_t)idx16 * 512 + lane * 8);
            }
#pragma unroll
            for (int pt = 0; pt < 2; ++pt)
#pragma unroll
                for (int nt = 0; nt < 4; ++nt)
                    acc[pt][nt] = __builtin_amdgcn_mfma_f32_16x16x32_bf16(a[pt], bf[nt], acc[pt][nt], 0, 0, 0);
        }
    }

    // ---- epilogue: relu(acc+bias), sum this wave's 32 positions ----
#pragma unroll
    for (int nt = 0; nt < 4; ++nt) {
        int k = kq * 64 + nt * 16 + lr;
        float bv = bias[k];
        float s = 0.f;
#pragma unroll
        for (int pt = 0; pt < 2; ++pt)
#pragma unroll
            for (int rr = 0; rr < 4; ++rr)
                s += fmaxf(acc[pt][nt][rr] + bv, 0.f);
        atomicAdd(&red[k], s);
    }
    __syncthreads();
    if (t < NK) atomicAdd(&Ssum[b * NK + t], red[t]);
}

// Per-(b,branch) MLP chain
__global__ __launch_bounds__(256) void chain_kernel(
    const float* __restrict__ Sy, const float* __restrict__ Sx1,
    const float* __restrict__ Sx2, const float* __restrict__ wd,
    const float* __restrict__ wc1, const float* __restrict__ bc1,
    const float* __restrict__ wc2, const float* __restrict__ bc2,
    float* __restrict__ sbr) {
    __shared__ float m[128];
    __shared__ float ap[512];
    __shared__ float z[128];
    const int b = blockIdx.x, br = blockIdx.y, t = threadIdx.x;
    const float* Sx = (br == 0) ? Sx1 : Sx2;
    const float inv = 1.0f / 4096.0f;

    if (t < 128) m[t] = (Sy[b * NK + t] + Sx[b * NK + t]) * inv;
    __syncthreads();
    for (int c = t; c < NC; c += 256) {
        float v = 0.f;
        for (int k = 0; k < NK; ++k) v += wd[c * NK + k] * m[k];
        ap[c] = v;
    }
    __syncthreads();
    if (t < 128) {
        float v = bc1[t];
        for (int c = 0; c < NC; ++c) v += wc1[t * NC + c] * ap[c];
        z[t] = fmaxf(v, 0.f);
    }
    __syncthreads();
    for (int c = t; c < NC; c += 256) {
        float v = bc2[c];
        for (int k = 0; k < NK; ++k) v += wc2[c * NK + k] * z[k];
        sbr[(br * NB + b) * NC + c] = 1.f / (1.f + expf(-v));
    }
}

// out[b,c,s] = x[b,c,s] + s1[b,c] + s2[b,c]
__global__ __launch_bounds__(256) void final_add(
    const float* __restrict__ x, const float* __restrict__ sbr,
    float* __restrict__ out) {
    const int total4 = NB * NC * SP / 4;   // 8388608
    for (int i = blockIdx.x * 256 + threadIdx.x; i < total4; i += gridDim.x * 256) {
        int flat = i * 4;
        int bc = flat >> 12;
        int b = bc >> 9, c = bc & 511;
        float s = sbr[b * NC + c] + sbr[NB * NC + b * NC + c];
        float4 xv = ((const float4*)x)[i];
        float4 o = {xv.x + s, xv.y + s, xv.z + s, xv.w + s};
        ((float4*)out)[i] = o;
    }
}

extern "C" void kernel_launch(void* const* d_in, const int* in_sizes, int n_in,
                              void* d_out, int out_size, void* d_ws, size_t ws_size,
                              hipStream_t stream) {
    const float* x   = (const float*)d_in[0];
    const float* wa  = (const float*)d_in[1];
    const float* ba  = (const float*)d_in[2];
    const float* wb  = (const float*)d_in[3];
    const float* bb  = (const float*)d_in[4];
    const float* wd  = (const float*)d_in[5];
    const float* wc1 = (const float*)d_in[6];
    const float* bc1 = (const float*)d_in[7];
    const float* wc2 = (const float*)d_in[8];
    const float* bc2 = (const float*)d_in[9];
    float* out = (float*)d_out;

    float* ws  = (float*)d_ws;
    float* SY  = ws;
    float* SX1 = ws + 2048;
    float* SX2 = ws + 4096;
    float* sbr = ws + 6144;
    unsigned short* wpre0 = (unsigned short*)(ws + 22528);
    unsigned short* wpre1 = (unsigned short*)(ws + 55296);

    hipMemsetAsync(ws, 0, 6144 * sizeof(float), stream);
    prep_weights<<<256, 256, 0, stream>>>(wa, wb, wpre0, wpre1);
    conv_v<0><<<dim3(64, NB), 256, 0, stream>>>(x, wpre0, bb, SY);
    conv_v<1><<<dim3(64, NB), 256, 0, stream>>>(x, wpre1, ba, SX1);
    conv_v<2><<<dim3(64, NB), 256, 0, stream>>>(x, wpre1, ba, SX2);
    chain_kernel<<<dim3(NB, 2), 256, 0, stream>>>(SY, SX1, SX2, wd, wc1, bc1, wc2, bc2, sbr);
    final_add<<<2048, 256, 0, stream>>>(x, sbr, out);
}

// Round 11
// 159.078 us; speedup vs baseline: 1.5921x; 1.0933x over previous
//
#include <hip/hip_runtime.h>
#include <math.h>

#define NB 16
#define NC 512
#define NK 128
#define SP 4096   // 64*64 spatial positions

typedef __attribute__((ext_vector_type(8))) short short8;
typedef __attribute__((ext_vector_type(4))) float f32x4;

__device__ inline unsigned short f2bf(float f) {
    unsigned int u = __builtin_bit_cast(unsigned int, f);
    u += 0x7fffu + ((u >> 16) & 1u);   // RNE
    return (unsigned short)(u >> 16);
}

// ---------------------------------------------------------------------------
// ws layout (float offsets):
//   [0..2047] SY  [2048..4095] SX1  [4096..6143] SX2
//   [6144..22527]  sbr (2 br * 16 b * 512 c)
//   [22528..55295] wpre0 : wb pre-swizzled to per-wave B-frag order (65536 u16)
//   [55296..88063] wpre1 : wa (col-permuted) same order             (65536 u16)
//
// wpre element order: o = idx16*512 + lane*8 + el, where
//   idx16 = (ch*4 + kk)*8 + t8   (t8 = global k-tile = kq*4+nt)
//   k = t8*16 + (lane&15);  i = ch*128 + kk*32 + (lane>>4)*8 + el
// so a B-frag load = one dwordx4 of 64 lanes x 16 B contiguous (1 KB line).
// For wpre1 the logical column i' maps to wa column 8*(i'&63) + (i'>>6)
// (the round-2/7/8-verified w1bf permutation).
// ---------------------------------------------------------------------------

__global__ __launch_bounds__(256) void prep_weights(
    const float* __restrict__ wa, const float* __restrict__ wb,
    unsigned short* __restrict__ w0, unsigned short* __restrict__ w1,
    float* __restrict__ zbase) {
    int o = blockIdx.x * 256 + threadIdx.x;   // 0..65535
    if (o < 6144) zbase[o] = 0.f;             // zero SY/SX1/SX2 (replaces memset)
    int idx16 = o >> 9;
    int lane = (o >> 3) & 63;
    int el = o & 7;
    int t8 = idx16 & 7;
    int kk = (idx16 >> 3) & 3;
    int ch = idx16 >> 5;
    int k = t8 * 16 + (lane & 15);
    int i = ch * 128 + kk * 32 + (lane >> 4) * 8 + el;
    w0[o] = f2bf(wb[k * 512 + i]);
    int col1 = 8 * (i & 63) + (i >> 6);
    w1[o] = f2bf(wa[k * 512 + col1]);
}

// ---------------------------------------------------------------------------
// Conv+mean body, round-2/7/8-verified fragment math. Block (g,b), 256 thr =
// 4 waves = (kq = wv>>1: k-half) x (po = wv&1: pos-half). LDS act [64 pos][128 i]
// bf16, XOR-swizzled 16B granules: byte(pos, iloc) =
//    pos*256 + (((iloc>>3) ^ (pos&7))<<4) + (iloc&7)*2
// A = act rows (pos), B = weight rows (k) from wpre (global, L2-hot);
// D col = k-local (lane&15), row = pos (4*lg+rr).
// VIEW 0: i = c = ch*128+iloc;            act elem = x[b, c, g*64+pos]
// VIEW 1: i'= 128ch+iloc (qh=iloc>>6,w=iloc&63): x[b, 64*(2ch+qh)+g, w, pos]
// VIEW 2: i'= 128ch+64qh+lane; pos=cl*8+jh:      x[b, 8g+cl, 8*(2ch+qh)+jh, lane]
// ---------------------------------------------------------------------------
template <int VIEW>
__device__ __forceinline__ void conv_body(
    const float* __restrict__ x, const unsigned short* __restrict__ wpre,
    const float* __restrict__ bias, float* __restrict__ Ssum,
    unsigned short* actS, float* red) {
    const int b = blockIdx.y;
    const int g = blockIdx.x;
    const int t = threadIdx.x;
    const int lane = t & 63;
    const int wv = t >> 6;
    const int kq = wv >> 1;      // k half: 4 nt-tiles
    const int po = wv & 1;       // pos half: 2 pt-tiles
    const int lr = lane & 15;
    const int lg = lane >> 4;

    if (t < NK) red[t] = 0.f;

    f32x4 acc[2][4];
#pragma unroll
    for (int pt = 0; pt < 2; ++pt)
#pragma unroll
        for (int nt = 0; nt < 4; ++nt) acc[pt][nt] = (f32x4)(0.f);

    for (int ch = 0; ch < 4; ++ch) {
        if (ch) __syncthreads();   // prior chunk's readers done before overwrite

        // ---- stage act tile [64 pos][128 i] ----
        if (VIEW <= 1) {
#pragma unroll
            for (int it = 0; it < 4; ++it) {
                int idx = it * 256 + t;        // 1024 granules
                int pos = idx & 63;            // = lane (coalesced loads)
                int gq = idx >> 6;             // 0..15, wave-uniform
                float v[8];
#pragma unroll
                for (int e = 0; e < 8; ++e) {
                    int iloc = 8 * gq + e;
                    size_t ga;
                    if (VIEW == 0) {
                        ga = (size_t)(b * NC + ch * 128 + iloc) * SP + g * 64 + pos;
                    } else {
                        int qh = iloc >> 6, w = iloc & 63;
                        ga = (size_t)(b * NC + 64 * (2 * ch + qh) + g) * SP + w * 64 + pos;
                    }
                    v[e] = x[ga];
                }
                short8 u;
#pragma unroll
                for (int e = 0; e < 8; ++e) u[e] = (short)f2bf(v[e]);
                int byte = pos * 256 + ((gq ^ (pos & 7)) << 4);
                *(short8*)((char*)actS + byte) = u;
            }
        } else {
            // verified scatter: lane -> iloc contiguous
#pragma unroll
            for (int r = wv; r < 128; r += 4) {
                int cl = r >> 4, jh = (r >> 1) & 7, qh = r & 1;
                size_t ga = (size_t)(b * NC + 8 * g + cl) * SP + (8 * (2 * ch + qh) + jh) * 64 + lane;
                unsigned short v = f2bf(x[ga]);
                int pos = cl * 8 + jh;
                int iloc = 64 * qh + lane;
                int byte = pos * 256 + (((iloc >> 3) ^ (pos & 7)) << 4) + (iloc & 7) * 2;
                *(unsigned short*)((char*)actS + byte) = v;
            }
        }
        __syncthreads();

        // ---- MFMA: A from LDS, B straight from wpre (1 KB coalesced) ----
#pragma unroll
        for (int kk = 0; kk < 4; ++kk) {
            const int ig = 4 * kk + lg;
            short8 a[2];
#pragma unroll
            for (int pt = 0; pt < 2; ++pt) {
                int prow = po * 32 + pt * 16 + lr;
                a[pt] = *(const short8*)((const char*)actS + prow * 256 + ((ig ^ (prow & 7)) << 4));
            }
            short8 bf[4];
#pragma unroll
            for (int nt = 0; nt < 4; ++nt) {
                int idx16 = (ch * 4 + kk) * 8 + kq * 4 + nt;
                bf[nt] = *(const short8*)(wpre + (size_t)idx16 * 512 + lane * 8);
            }
#pragma unroll
            for (int pt = 0; pt < 2; ++pt)
#pragma unroll
                for (int nt = 0; nt < 4; ++nt)
                    acc[pt][nt] = __builtin_amdgcn_mfma_f32_16x16x32_bf16(a[pt], bf[nt], acc[pt][nt], 0, 0, 0);
        }
    }

    // ---- epilogue: relu(acc+bias), sum this wave's 32 positions ----
#pragma unroll
    for (int nt = 0; nt < 4; ++nt) {
        int k = kq * 64 + nt * 16 + lr;
        float bv = bias[k];
        float s = 0.f;
#pragma unroll
        for (int pt = 0; pt < 2; ++pt)
#pragma unroll
            for (int rr = 0; rr < 4; ++rr)
                s += fmaxf(acc[pt][nt][rr] + bv, 0.f);
        atomicAdd(&red[k], s);
    }
    __syncthreads();
    if (t < NK) atomicAdd(&Ssum[b * NK + t], red[t]);
}

// Merged conv launch: blockIdx.z selects the view (block-uniform branch).
__global__ __launch_bounds__(256, 4) void conv_all(
    const float* __restrict__ x,
    const unsigned short* __restrict__ wpre0, const unsigned short* __restrict__ wpre1,
    const float* __restrict__ bb, const float* __restrict__ ba,
    float* __restrict__ SY, float* __restrict__ SX1, float* __restrict__ SX2) {
    __shared__ __align__(16) unsigned short actS[64 * 128];   // 16 KB
    __shared__ float red[NK];
    const int view = blockIdx.z;
    if (view == 0)      conv_body<0>(x, wpre0, bb, SY,  actS, red);
    else if (view == 1) conv_body<1>(x, wpre1, ba, SX1, actS, red);
    else                conv_body<2>(x, wpre1, ba, SX2, actS, red);
}

// Per-(b,branch) MLP chain
__global__ __launch_bounds__(256) void chain_kernel(
    const float* __restrict__ Sy, const float* __restrict__ Sx1,
    const float* __restrict__ Sx2, const float* __restrict__ wd,
    const float* __restrict__ wc1, const float* __restrict__ bc1,
    const float* __restrict__ wc2, const float* __restrict__ bc2,
    float* __restrict__ sbr) {
    __shared__ float m[128];
    __shared__ float ap[512];
    __shared__ float z[128];
    const int b = blockIdx.x, br = blockIdx.y, t = threadIdx.x;
    const float* Sx = (br == 0) ? Sx1 : Sx2;
    const float inv = 1.0f / 4096.0f;

    if (t < 128) m[t] = (Sy[b * NK + t] + Sx[b * NK + t]) * inv;
    __syncthreads();
    for (int c = t; c < NC; c += 256) {
        float v = 0.f;
        for (int k = 0; k < NK; ++k) v += wd[c * NK + k] * m[k];
        ap[c] = v;
    }
    __syncthreads();
    if (t < 128) {
        float v = bc1[t];
        for (int c = 0; c < NC; ++c) v += wc1[t * NC + c] * ap[c];
        z[t] = fmaxf(v, 0.f);
    }
    __syncthreads();
    for (int c = t; c < NC; c += 256) {
        float v = bc2[c];
        for (int k = 0; k < NK; ++k) v += wc2[c * NK + k] * z[k];
        sbr[(br * NB + b) * NC + c] = 1.f / (1.f + expf(-v));
    }
}

// out[b,c,s] = x[b,c,s] + s1[b,c] + s2[b,c]  (streaming: nontemporal x/out)
__global__ __launch_bounds__(256) void final_add(
    const float* __restrict__ x, const float* __restrict__ sbr,
    float* __restrict__ out) {
    const int total4 = NB * NC * SP / 4;   // 8388608
    for (int i = blockIdx.x * 256 + threadIdx.x; i < total4; i += gridDim.x * 256) {
        int flat = i * 4;
        int bc = flat >> 12;
        int b = bc >> 9, c = bc & 511;
        float s = sbr[b * NC + c] + sbr[NB * NC + b * NC + c];
        f32x4 xv = __builtin_nontemporal_load((const f32x4*)x + i);
        f32x4 o = {xv.x + s, xv.y + s, xv.z + s, xv.w + s};
        __builtin_nontemporal_store(o, (f32x4*)out + i);
    }
}

extern "C" void kernel_launch(void* const* d_in, const int* in_sizes, int n_in,
                              void* d_out, int out_size, void* d_ws, size_t ws_size,
                              hipStream_t stream) {
    const float* x   = (const float*)d_in[0];
    const float* wa  = (const float*)d_in[1];
    const float* ba  = (const float*)d_in[2];
    const float* wb  = (const float*)d_in[3];
    const float* bb  = (const float*)d_in[4];
    const float* wd  = (const float*)d_in[5];
    const float* wc1 = (const float*)d_in[6];
    const float* bc1 = (const float*)d_in[7];
    const float* wc2 = (const float*)d_in[8];
    const float* bc2 = (const float*)d_in[9];
    float* out = (float*)d_out;

    float* ws  = (float*)d_ws;
    float* SY  = ws;
    float* SX1 = ws + 2048;
    float* SX2 = ws + 4096;
    float* sbr = ws + 6144;
    unsigned short* wpre0 = (unsigned short*)(ws + 22528);
    unsigned short* wpre1 = (unsigned short*)(ws + 55296);

    prep_weights<<<256, 256, 0, stream>>>(wa, wb, wpre0, wpre1, ws);
    conv_all<<<dim3(64, NB, 3), 256, 0, stream>>>(x, wpre0, wpre1, bb, ba, SY, SX1, SX2);
    chain_kernel<<<dim3(NB, 2), 256, 0, stream>>>(SY, SX1, SX2, wd, wc1, bc1, wc2, bc2, sbr);
    final_add<<<2048, 256, 0, stream>>>(x, sbr, out);
}

// Round 12
// 154.992 us; speedup vs baseline: 1.6341x; 1.0264x over previous
//
#include <hip/hip_runtime.h>
#include <math.h>

#define NB 16
#define NC 512
#define NK 128
#define SP 4096   // 64*64 spatial positions

typedef __attribute__((ext_vector_type(8))) short short8;
typedef __attribute__((ext_vector_type(4))) float f32x4;

__device__ inline unsigned short f2bf(float f) {
    unsigned int u = __builtin_bit_cast(unsigned int, f);
    u += 0x7fffu + ((u >> 16) & 1u);   // RNE
    return (unsigned short)(u >> 16);
}

// LDS act layout: byte(pos, iloc) = pos*256 + (G<<4) + (iloc&7)*2,
//   G = (iloc>>3) ^ (pos&7) ^ ((pos>>3)&7)
// The extra (pos>>3) XOR term spreads float4-staged writes (pos = 4*h4+m)
// across 8 granules per quarter-wave (2-way, free); A-frag b128 reads stay 2-way.
__device__ __forceinline__ int swzbyte(int pos, int iloc) {
    return pos * 256 + ((((iloc >> 3) ^ (pos & 7) ^ ((pos >> 3) & 7)) & 15) << 4) + (iloc & 7) * 2;
}

// ---------------------------------------------------------------------------
// ws layout (float offsets):
//   [0..2047] SY  [2048..4095] SX1  [4096..6143] SX2
//   [6144..22527]  sbr (2 br * 16 b * 512 c)
//   [22528..55295] wpre0 : wb pre-swizzled to per-wave B-frag order (65536 u16)
//   [55296..88063] wpre1 : wa (col-permuted) same order             (65536 u16)
//
// wpre element order: o = idx16*512 + lane*8 + el, where
//   idx16 = (ch*4 + kk)*8 + t8   (t8 = global k-tile = kq*4+nt)
//   k = t8*16 + (lane&15);  i = ch*128 + kk*32 + (lane>>4)*8 + el
// For wpre1 the logical column i' maps to wa column 8*(i'&63) + (i'>>6).
// ---------------------------------------------------------------------------

__global__ __launch_bounds__(256) void prep_weights(
    const float* __restrict__ wa, const float* __restrict__ wb,
    unsigned short* __restrict__ w0, unsigned short* __restrict__ w1,
    float* __restrict__ zbase) {
    int o = blockIdx.x * 256 + threadIdx.x;   // 0..65535
    if (o < 6144) zbase[o] = 0.f;             // zero SY/SX1/SX2 (replaces memset)
    int idx16 = o >> 9;
    int lane = (o >> 3) & 63;
    int el = o & 7;
    int t8 = idx16 & 7;
    int kk = (idx16 >> 3) & 3;
    int ch = idx16 >> 5;
    int k = t8 * 16 + (lane & 15);
    int i = ch * 128 + kk * 32 + (lane >> 4) * 8 + el;
    w0[o] = f2bf(wb[k * 512 + i]);
    int col1 = 8 * (i & 63) + (i >> 6);
    w1[o] = f2bf(wa[k * 512 + col1]);
}

// ---------------------------------------------------------------------------
// Conv+mean body, round-2/7/8-verified fragment math; staging via float4-
// along-h loads (8 independent dwordx4 per thread per chunk) + swizzled
// scatter writes. Block (g,b), 256 thr = 4 waves = (kq = wv>>1) x (po = wv&1).
// VIEW 0: i = c = ch*128+iloc;            act elem = x[b, c, g, h=pos]
// VIEW 1: i'= 128ch+iloc (qh=iloc>>6,w=iloc&63): x[b, 64*(2ch+qh)+g, w, h=pos]
// VIEW 2: i'= 128ch+64qh+(h); pos=cl*8+jh:       x[b, 8g+cl, 8*(2ch+qh)+jh, h]
// ---------------------------------------------------------------------------
template <int VIEW>
__device__ __forceinline__ void conv_body(
    const float* __restrict__ x, const unsigned short* __restrict__ wpre,
    const float* __restrict__ bias, float* __restrict__ Ssum,
    unsigned short* actS, float* red) {
    const int b = blockIdx.y;
    const int g = blockIdx.x;
    const int t = threadIdx.x;
    const int lane = t & 63;
    const int wv = t >> 6;
    const int kq = wv >> 1;      // k half: 4 nt-tiles
    const int po = wv & 1;       // pos half: 2 pt-tiles
    const int lr = lane & 15;
    const int lg = lane >> 4;

    if (t < NK) red[t] = 0.f;

    f32x4 acc[2][4];
#pragma unroll
    for (int pt = 0; pt < 2; ++pt)
#pragma unroll
        for (int nt = 0; nt < 4; ++nt) acc[pt][nt] = (f32x4)(0.f);

    for (int ch = 0; ch < 4; ++ch) {
        if (ch) __syncthreads();   // prior chunk's readers done before overwrite

        // ---- stage act tile [64 pos][128 i]: 8 float4 loads per thread ----
        if (VIEW <= 1) {
#pragma unroll
            for (int it = 0; it < 8; ++it) {
                int idx = it * 256 + t;        // 2048 float4
                int h4 = idx & 15;             // 16 float4 per h-row
                int iloc = idx >> 4;           // 0..127
                size_t ga;
                if (VIEW == 0) {
                    ga = (size_t)(b * NC + ch * 128 + iloc) * SP + g * 64 + h4 * 4;
                } else {
                    int qh = iloc >> 6, w = iloc & 63;
                    ga = (size_t)(b * NC + 64 * (2 * ch + qh) + g) * SP + w * 64 + h4 * 4;
                }
                f32x4 v = *(const f32x4*)(x + ga);
#pragma unroll
                for (int m = 0; m < 4; ++m) {
                    int pos = h4 * 4 + m;
                    *(unsigned short*)((char*)actS + swzbyte(pos, iloc)) = f2bf(v[m]);
                }
            }
        } else {
#pragma unroll
            for (int it = 0; it < 8; ++it) {
                int idx = it * 256 + t;        // 2048 float4
                int u = idx & 15;              // h quad
                int r = idx >> 4;              // 0..127
                int cl = r >> 4, jh = (r >> 1) & 7, qh = r & 1;
                size_t ga = (size_t)(b * NC + 8 * g + cl) * SP + (8 * (2 * ch + qh) + jh) * 64 + 4 * u;
                f32x4 v = *(const f32x4*)(x + ga);
                int pos = cl * 8 + jh;
                int iloc = 64 * qh + 4 * u;
                ushort4 uu;
                uu.x = f2bf(v.x); uu.y = f2bf(v.y); uu.z = f2bf(v.z); uu.w = f2bf(v.w);
                *(ushort4*)((char*)actS + swzbyte(pos, iloc)) = uu;
            }
        }
        __syncthreads();

        // ---- MFMA: A from LDS, B straight from wpre (1 KB coalesced) ----
#pragma unroll
        for (int kk = 0; kk < 4; ++kk) {
            const int ig = 4 * kk + lg;
            short8 a[2];
#pragma unroll
            for (int pt = 0; pt < 2; ++pt) {
                int prow = po * 32 + pt * 16 + lr;
                a[pt] = *(const short8*)((const char*)actS + swzbyte(prow, ig * 8));
            }
            short8 bf[4];
#pragma unroll
            for (int nt = 0; nt < 4; ++nt) {
                int idx16 = (ch * 4 + kk) * 8 + kq * 4 + nt;
                bf[nt] = *(const short8*)(wpre + (size_t)idx16 * 512 + lane * 8);
            }
#pragma unroll
            for (int pt = 0; pt < 2; ++pt)
#pragma unroll
                for (int nt = 0; nt < 4; ++nt)
                    acc[pt][nt] = __builtin_amdgcn_mfma_f32_16x16x32_bf16(a[pt], bf[nt], acc[pt][nt], 0, 0, 0);
        }
    }

    // ---- epilogue: relu(acc+bias), sum this wave's 32 positions ----
#pragma unroll
    for (int nt = 0; nt < 4; ++nt) {
        int k = kq * 64 + nt * 16 + lr;
        float bv = bias[k];
        float s = 0.f;
#pragma unroll
        for (int pt = 0; pt < 2; ++pt)
#pragma unroll
            for (int rr = 0; rr < 4; ++rr)
                s += fmaxf(acc[pt][nt][rr] + bv, 0.f);
        atomicAdd(&red[k], s);
    }
    __syncthreads();
    if (t < NK) atomicAdd(&Ssum[b * NK + t], red[t]);
}

// Merged conv launch: blockIdx.z selects the view (block-uniform branch).
__global__ __launch_bounds__(256, 4) void conv_all(
    const float* __restrict__ x,
    const unsigned short* __restrict__ wpre0, const unsigned short* __restrict__ wpre1,
    const float* __restrict__ bb, const float* __restrict__ ba,
    float* __restrict__ SY, float* __restrict__ SX1, float* __restrict__ SX2) {
    __shared__ __align__(16) unsigned short actS[64 * 128];   // 16 KB
    __shared__ float red[NK];
    const int view = blockIdx.z;
    if (view == 0)      conv_body<0>(x, wpre0, bb, SY,  actS, red);
    else if (view == 1) conv_body<1>(x, wpre1, ba, SX1, actS, red);
    else                conv_body<2>(x, wpre1, ba, SX2, actS, red);
}

// Per-(b,branch) MLP chain
__global__ __launch_bounds__(256) void chain_kernel(
    const float* __restrict__ Sy, const float* __restrict__ Sx1,
    const float* __restrict__ Sx2, const float* __restrict__ wd,
    const float* __restrict__ wc1, const float* __restrict__ bc1,
    const float* __restrict__ wc2, const float* __restrict__ bc2,
    float* __restrict__ sbr) {
    __shared__ float m[128];
    __shared__ float ap[512];
    __shared__ float z[128];
    const int b = blockIdx.x, br = blockIdx.y, t = threadIdx.x;
    const float* Sx = (br == 0) ? Sx1 : Sx2;
    const float inv = 1.0f / 4096.0f;

    if (t < 128) m[t] = (Sy[b * NK + t] + Sx[b * NK + t]) * inv;
    __syncthreads();
    for (int c = t; c < NC; c += 256) {
        float v = 0.f;
        for (int k = 0; k < NK; ++k) v += wd[c * NK + k] * m[k];
        ap[c] = v;
    }
    __syncthreads();
    if (t < 128) {
        float v = bc1[t];
        for (int c = 0; c < NC; ++c) v += wc1[t * NC + c] * ap[c];
        z[t] = fmaxf(v, 0.f);
    }
    __syncthreads();
    for (int c = t; c < NC; c += 256) {
        float v = bc2[c];
        for (int k = 0; k < NK; ++k) v += wc2[c * NK + k] * z[k];
        sbr[(br * NB + b) * NC + c] = 1.f / (1.f + expf(-v));
    }
}

// out[b,c,s] = x[b,c,s] + s1[b,c] + s2[b,c]  (streaming: nontemporal x/out)
__global__ __launch_bounds__(256) void final_add(
    const float* __restrict__ x, const float* __restrict__ sbr,
    float* __restrict__ out) {
    const int total4 = NB * NC * SP / 4;   // 8388608
    for (int i = blockIdx.x * 256 + threadIdx.x; i < total4; i += gridDim.x * 256) {
        int flat = i * 4;
        int bc = flat >> 12;
        int b = bc >> 9, c = bc & 511;
        float s = sbr[b * NC + c] + sbr[NB * NC + b * NC + c];
        f32x4 xv = __builtin_nontemporal_load((const f32x4*)x + i);
        f32x4 o = {xv.x + s, xv.y + s, xv.z + s, xv.w + s};
        __builtin_nontemporal_store(o, (f32x4*)out + i);
    }
}

extern "C" void kernel_launch(void* const* d_in, const int* in_sizes, int n_in,
                              void* d_out, int out_size, void* d_ws, size_t ws_size,
                              hipStream_t stream) {
    const float* x   = (const float*)d_in[0];
    const float* wa  = (const float*)d_in[1];
    const float* ba  = (const float*)d_in[2];
    const float* wb  = (const float*)d_in[3];
    const float* bb  = (const float*)d_in[4];
    const float* wd  = (const float*)d_in[5];
    const float* wc1 = (const float*)d_in[6];
    const float* bc1 = (const float*)d_in[7];
    const float* wc2 = (const float*)d_in[8];
    const float* bc2 = (const float*)d_in[9];
    float* out = (float*)d_out;

    float* ws  = (float*)d_ws;
    float* SY  = ws;
    float* SX1 = ws + 2048;
    float* SX2 = ws + 4096;
    float* sbr = ws + 6144;
    unsigned short* wpre0 = (unsigned short*)(ws + 22528);
    unsigned short* wpre1 = (unsigned short*)(ws + 55296);

    prep_weights<<<256, 256, 0, stream>>>(wa, wb, wpre0, wpre1, ws);
    conv_all<<<dim3(64, NB, 3), 256, 0, stream>>>(x, wpre0, wpre1, bb, ba, SY, SX1, SX2);
    chain_kernel<<<dim3(NB, 2), 256, 0, stream>>>(SY, SX1, SX2, wd, wc1, bc1, wc2, bc2, sbr);
    final_add<<<2048, 256, 0, stream>>>(x, sbr, out);
}

// Round 13
// 143.915 us; speedup vs baseline: 1.7598x; 1.0770x over previous
//
#include <hip/hip_runtime.h>
#include <math.h>

#define NB 16
#define NC 512
#define NK 128
#define SP 4096   // 64*64 spatial positions

typedef __attribute__((ext_vector_type(8))) short short8;
typedef __attribute__((ext_vector_type(4))) float f32x4;

__device__ inline unsigned short f2bf(float f) {
    unsigned int u = __builtin_bit_cast(unsigned int, f);
    u += 0x7fffu + ((u >> 16) & 1u);   // RNE
    return (unsigned short)(u >> 16);
}

// LDS act layout: byte(pos, iloc) = pos*256 + (G<<4) + (iloc&7)*2,
//   G = (iloc>>3) ^ (pos&7) ^ ((pos>>3)&7)
__device__ __forceinline__ int swzbyte(int pos, int iloc) {
    return pos * 256 + ((((iloc >> 3) ^ (pos & 7) ^ ((pos >> 3) & 7)) & 15) << 4) + (iloc & 7) * 2;
}

// ---------------------------------------------------------------------------
// ws layout (float offsets):
//   [0..2047] SY  [2048..4095] SX1  [4096..6143] SX2
//   [6144..22527]  sbr (2 br * 16 b * 512 c)
//   [22528..55295] wpre0 : wb pre-swizzled to per-wave B-frag order (65536 u16)
//   [55296..88063] wpre1 : wa (col-permuted) same order             (65536 u16)
//
// wpre element order: o = idx16*512 + lane*8 + el, where
//   idx16 = (ch*4 + kk)*8 + t8   (t8 = global k-tile = kq*4+nt)
//   k = t8*16 + (lane&15);  i = ch*128 + kk*32 + (lane>>4)*8 + el
// For wpre1 the logical column i' maps to wa column 8*(i'&63) + (i'>>6).
// ---------------------------------------------------------------------------

__global__ __launch_bounds__(256) void prep_weights(
    const float* __restrict__ wa, const float* __restrict__ wb,
    unsigned short* __restrict__ w0, unsigned short* __restrict__ w1,
    float* __restrict__ zbase) {
    int o = blockIdx.x * 256 + threadIdx.x;   // 0..65535
    if (o < 6144) zbase[o] = 0.f;             // zero SY/SX1/SX2 (replaces memset)
    int idx16 = o >> 9;
    int lane = (o >> 3) & 63;
    int el = o & 7;
    int t8 = idx16 & 7;
    int kk = (idx16 >> 3) & 3;
    int ch = idx16 >> 5;
    int k = t8 * 16 + (lane & 15);
    int i = ch * 128 + kk * 32 + (lane >> 4) * 8 + el;
    w0[o] = f2bf(wb[k * 512 + i]);
    int col1 = 8 * (i & 63) + (i >> 6);
    w1[o] = f2bf(wa[k * 512 + col1]);
}

// ---------------------------------------------------------------------------
// Conv+mean body, round-2/7/8-verified fragment math. Staging: 4-row register
// transpose -> ushort4 b64 LDS writes. Block (g,b), 256 thr = 4 waves =
// (kq = wv>>1) x (po = wv&1).
// VIEW 0: i = c = ch*128+iloc;            act elem = x[b, c, g, h=pos]
// VIEW 1: i'= 128ch+iloc (qh=iloc>>6,w=iloc&63): x[b, 64*(2ch+qh)+g, w, h=pos]
// VIEW 2: i'= 128ch+64qh+(h); pos=cl*8+jh:       x[b, 8g+cl, 8*(2ch+qh)+jh, h]
// ---------------------------------------------------------------------------
template <int VIEW>
__device__ __forceinline__ void conv_body(
    const float* __restrict__ x, const unsigned short* __restrict__ wpre,
    const float* __restrict__ bias, float* __restrict__ Ssum,
    unsigned short* actS, float* red) {
    const int b = blockIdx.y;
    const int g = blockIdx.x;
    const int t = threadIdx.x;
    const int lane = t & 63;
    const int wv = t >> 6;
    const int kq = wv >> 1;      // k half: 4 nt-tiles
    const int po = wv & 1;       // pos half: 2 pt-tiles
    const int lr = lane & 15;
    const int lg = lane >> 4;

    if (t < NK) red[t] = 0.f;

    f32x4 acc[2][4];
#pragma unroll
    for (int pt = 0; pt < 2; ++pt)
#pragma unroll
        for (int nt = 0; nt < 4; ++nt) acc[pt][nt] = (f32x4)(0.f);

    for (int ch = 0; ch < 4; ++ch) {
        if (ch) __syncthreads();   // prior chunk's readers done before overwrite

        // ---- stage act tile [64 pos][128 i] ----
        if (VIEW <= 1) {
            // 2 groups/thread: 4 row-adjacent float4 loads -> 4x4 register
            // transpose -> 4 ushort4 b64 writes (iloc-contiguous).
#pragma unroll
            for (int grp = 0; grp < 2; ++grp) {
                int gi = grp * 256 + t;     // 512 groups
                int cq = gi & 15;           // col quad -> pos 4cq..+3
                int rq = gi >> 4;           // 0..31 -> rows 4rq..+3
                f32x4 v[4];
#pragma unroll
                for (int j = 0; j < 4; ++j) {
                    int row = 4 * rq + j;
                    size_t ga;
                    if (VIEW == 0) {
                        ga = (size_t)(b * NC + ch * 128 + row) * SP + g * 64 + 4 * cq;
                    } else {
                        int qh = row >> 6, w = row & 63;
                        ga = (size_t)(b * NC + 64 * (2 * ch + qh) + g) * SP + w * 64 + 4 * cq;
                    }
                    v[j] = *(const f32x4*)(x + ga);
                }
#pragma unroll
                for (int m = 0; m < 4; ++m) {
                    int pos = 4 * cq + m;
                    ushort4 u;
                    u.x = f2bf(v[0][m]); u.y = f2bf(v[1][m]);
                    u.z = f2bf(v[2][m]); u.w = f2bf(v[3][m]);
                    *(ushort4*)((char*)actS + swzbyte(pos, 4 * rq)) = u;
                }
            }
        } else {
#pragma unroll
            for (int it = 0; it < 8; ++it) {
                int idx = it * 256 + t;        // 2048 float4
                int u = idx & 15;              // h quad
                int r = idx >> 4;              // 0..127
                int cl = r >> 4, jh = (r >> 1) & 7, qh = r & 1;
                size_t ga = (size_t)(b * NC + 8 * g + cl) * SP + (8 * (2 * ch + qh) + jh) * 64 + 4 * u;
                f32x4 v = *(const f32x4*)(x + ga);
                int pos = cl * 8 + jh;
                int iloc = 64 * qh + 4 * u;
                ushort4 uu;
                uu.x = f2bf(v.x); uu.y = f2bf(v.y); uu.z = f2bf(v.z); uu.w = f2bf(v.w);
                *(ushort4*)((char*)actS + swzbyte(pos, iloc)) = uu;
            }
        }
        __syncthreads();

        // ---- MFMA: A from LDS, B straight from wpre (1 KB coalesced) ----
#pragma unroll
        for (int kk = 0; kk < 4; ++kk) {
            const int ig = 4 * kk + lg;
            short8 a[2];
#pragma unroll
            for (int pt = 0; pt < 2; ++pt) {
                int prow = po * 32 + pt * 16 + lr;
                a[pt] = *(const short8*)((const char*)actS + swzbyte(prow, ig * 8));
            }
            short8 bf[4];
#pragma unroll
            for (int nt = 0; nt < 4; ++nt) {
                int idx16 = (ch * 4 + kk) * 8 + kq * 4 + nt;
                bf[nt] = *(const short8*)(wpre + (size_t)idx16 * 512 + lane * 8);
            }
#pragma unroll
            for (int pt = 0; pt < 2; ++pt)
#pragma unroll
                for (int nt = 0; nt < 4; ++nt)
                    acc[pt][nt] = __builtin_amdgcn_mfma_f32_16x16x32_bf16(a[pt], bf[nt], acc[pt][nt], 0, 0, 0);
        }
    }

    // ---- epilogue: relu(acc+bias); pos-partials reduced across lg by shfl,
    // one LDS atomic per (nt, lr) per wave (4x fewer atomics) ----
#pragma unroll
    for (int nt = 0; nt < 4; ++nt) {
        int k = kq * 64 + nt * 16 + lr;
        float bv = bias[k];
        float s = 0.f;
#pragma unroll
        for (int pt = 0; pt < 2; ++pt)
#pragma unroll
            for (int rr = 0; rr < 4; ++rr)
                s += fmaxf(acc[pt][nt][rr] + bv, 0.f);
        s += __shfl_xor(s, 16);
        s += __shfl_xor(s, 32);
        if (lg == 0) atomicAdd(&red[k], s);
    }
    __syncthreads();
    if (t < NK) atomicAdd(&Ssum[b * NK + t], red[t]);
}

// Merged conv launch: blockIdx.z selects the view (block-uniform branch).
__global__ __launch_bounds__(256, 4) void conv_all(
    const float* __restrict__ x,
    const unsigned short* __restrict__ wpre0, const unsigned short* __restrict__ wpre1,
    const float* __restrict__ bb, const float* __restrict__ ba,
    float* __restrict__ SY, float* __restrict__ SX1, float* __restrict__ SX2) {
    __shared__ __align__(16) unsigned short actS[64 * 128];   // 16 KB
    __shared__ float red[NK];
    const int view = blockIdx.z;
    if (view == 0)      conv_body<0>(x, wpre0, bb, SY,  actS, red);
    else if (view == 1) conv_body<1>(x, wpre1, ba, SX1, actS, red);
    else                conv_body<2>(x, wpre1, ba, SX2, actS, red);
}

// Per-(b,branch) MLP chain
__global__ __launch_bounds__(256) void chain_kernel(
    const float* __restrict__ Sy, const float* __restrict__ Sx1,
    const float* __restrict__ Sx2, const float* __restrict__ wd,
    const float* __restrict__ wc1, const float* __restrict__ bc1,
    const float* __restrict__ wc2, const float* __restrict__ bc2,
    float* __restrict__ sbr) {
    __shared__ float m[128];
    __shared__ float ap[512];
    __shared__ float z[128];
    const int b = blockIdx.x, br = blockIdx.y, t = threadIdx.x;
    const float* Sx = (br == 0) ? Sx1 : Sx2;
    const float inv = 1.0f / 4096.0f;

    if (t < 128) m[t] = (Sy[b * NK + t] + Sx[b * NK + t]) * inv;
    __syncthreads();
    for (int c = t; c < NC; c += 256) {
        float v = 0.f;
        for (int k = 0; k < NK; ++k) v += wd[c * NK + k] * m[k];
        ap[c] = v;
    }
    __syncthreads();
    if (t < 128) {
        float v = bc1[t];
        for (int c = 0; c < NC; ++c) v += wc1[t * NC + c] * ap[c];
        z[t] = fmaxf(v, 0.f);
    }
    __syncthreads();
    for (int c = t; c < NC; c += 256) {
        float v = bc2[c];
        for (int k = 0; k < NK; ++k) v += wc2[c * NK + k] * z[k];
        sbr[(br * NB + b) * NC + c] = 1.f / (1.f + expf(-v));
    }
}

// out[b,c,s] = x[b,c,s] + s1[b,c] + s2[b,c]  (streaming: nontemporal x/out)
__global__ __launch_bounds__(256) void final_add(
    const float* __restrict__ x, const float* __restrict__ sbr,
    float* __restrict__ out) {
    const int total4 = NB * NC * SP / 4;   // 8388608
    for (int i = blockIdx.x * 256 + threadIdx.x; i < total4; i += gridDim.x * 256) {
        int flat = i * 4;
        int bc = flat >> 12;
        int b = bc >> 9, c = bc & 511;
        float s = sbr[b * NC + c] + sbr[NB * NC + b * NC + c];
        f32x4 xv = __builtin_nontemporal_load((const f32x4*)x + i);
        f32x4 o = {xv.x + s, xv.y + s, xv.z + s, xv.w + s};
        __builtin_nontemporal_store(o, (f32x4*)out + i);
    }
}

extern "C" void kernel_launch(void* const* d_in, const int* in_sizes, int n_in,
                              void* d_out, int out_size, void* d_ws, size_t ws_size,
                              hipStream_t stream) {
    const float* x   = (const float*)d_in[0];
    const float* wa  = (const float*)d_in[1];
    const float* ba  = (const float*)d_in[2];
    const float* wb  = (const float*)d_in[3];
    const float* bb  = (const float*)d_in[4];
    const float* wd  = (const float*)d_in[5];
    const float* wc1 = (const float*)d_in[6];
    const float* bc1 = (const float*)d_in[7];
    const float* wc2 = (const float*)d_in[8];
    const float* bc2 = (const float*)d_in[9];
    float* out = (float*)d_out;

    float* ws  = (float*)d_ws;
    float* SY  = ws;
    float* SX1 = ws + 2048;
    float* SX2 = ws + 4096;
    float* sbr = ws + 6144;
    unsigned short* wpre0 = (unsigned short*)(ws + 22528);
    unsigned short* wpre1 = (unsigned short*)(ws + 55296);

    prep_weights<<<256, 256, 0, stream>>>(wa, wb, wpre0, wpre1, ws);
    conv_all<<<dim3(64, NB, 3), 256, 0, stream>>>(x, wpre0, wpre1, bb, ba, SY, SX1, SX2);
    chain_kernel<<<dim3(NB, 2), 256, 0, stream>>>(SY, SX1, SX2, wd, wc1, bc1, wc2, bc2, sbr);
    final_add<<<2048, 256, 0, stream>>>(x, sbr, out);
}